// Round 10
// baseline (816.889 us; speedup 1.0000x reference)
//
#include <hip/hip_runtime.h>
#include <hip/hip_cooperative_groups.h>
#include <hip/hip_bf16.h>

namespace cg = cooperative_groups;

#define N_NODES 8192
#define F_IN    512
#define F_HID   256
#define ALPHA   0.2f
#define MAXDEG  64
#define SMEM_BYTES 27648
#define GRID_COOP 1024

using f32x4 = __attribute__((ext_vector_type(4))) float;
using f16x8 = __attribute__((ext_vector_type(8))) _Float16;
using f16x4 = __attribute__((ext_vector_type(4))) _Float16;

struct GP {
    const float *x, *adj, *W1, *a1, *W2, *a2;
    float *dec, *enc;
    int *cols, *cnt;
    float *s1, *t1, *s2, *t2, *w2s, *w2t;
    _Float16 *Wh1, *enc16, *aggE16, *W1T, *W2T;
};

// ---------------------------------------------------------------------------
// prep job t in [0,260): t<128 W1-transpose tile, t<256 W2 tile, else w2s/w2t.
// ---------------------------------------------------------------------------
__device__ void prep_job(int t, char* smem, const GP& p) {
    const int tid = threadIdx.x;
    if (t >= 256) {
        const int r = (t - 256) * 64 + (tid >> 2);
        const int q = tid & 3;
        float ss = 0.f, tt = 0.f;
        for (int n = q * 4; n < F_IN; n += 16) {
            f32x4 w  = *(const f32x4*)&p.W2[(size_t)r * F_IN + n];
            f32x4 as = *(const f32x4*)&p.a2[n];
            f32x4 at = *(const f32x4*)&p.a2[F_IN + n];
            #pragma unroll
            for (int j = 0; j < 4; ++j) { ss += w[j] * as[j]; tt += w[j] * at[j]; }
        }
        ss += __shfl_xor(ss, 1); ss += __shfl_xor(ss, 2);
        tt += __shfl_xor(tt, 1); tt += __shfl_xor(tt, 2);
        if (q == 0) { p.w2s[r] = ss; p.w2t[r] = tt; }
        return;
    }
    const float* W; _Float16* WT; int K, N, kt, nt;
    if (t < 128) { W = p.W1; WT = p.W1T; K = 512; N = 256; kt = t & 15; nt = t >> 4; }
    else { int u = t - 128; W = p.W2; WT = p.W2T; K = 256; N = 512; kt = u & 7; nt = u >> 3; }
    float (*Ws)[33] = (float(*)[33])smem;
    const int tx = tid & 31, ty = tid >> 5;  // 32 x 8
    #pragma unroll
    for (int i = 0; i < 4; ++i)
        Ws[ty + 8 * i][tx] = W[(size_t)(kt * 32 + ty + 8 * i) * N + nt * 32 + tx];
    __syncthreads();
    #pragma unroll
    for (int i = 0; i < 4; ++i)
        WT[(size_t)(nt * 32 + ty + 8 * i) * K + kt * 32 + tx] = (_Float16)Ws[tx][ty + 8 * i];
    __syncthreads();
}

// ---------------------------------------------------------------------------
// CSR row scan: one wave per adjacency row, 2 x f32x4 NT loads per iter.
// ---------------------------------------------------------------------------
__device__ void csr_row(const float* __restrict__ adj, int* __restrict__ cols,
                        int* __restrict__ cnt, int row, int lane) {
    const f32x4* arow = (const f32x4*)(adj + (size_t)row * N_NODES);
    int* crow = cols + (size_t)row * MAXDEG;
    int count = 0;
    const unsigned long long mlt = (1ULL << lane) - 1ULL;
    for (int base = 0; base < N_NODES; base += 512) {
        f32x4 v0 = __builtin_nontemporal_load(&arow[(base >> 2) + lane]);
        f32x4 v1 = __builtin_nontemporal_load(&arow[(base >> 2) + 64 + lane]);
        unsigned long long b0 = __ballot(v0[0] > 0.0f);
        unsigned long long b1 = __ballot(v0[1] > 0.0f);
        unsigned long long b2 = __ballot(v0[2] > 0.0f);
        unsigned long long b3 = __ballot(v0[3] > 0.0f);
        unsigned long long b4 = __ballot(v1[0] > 0.0f);
        unsigned long long b5 = __ballot(v1[1] > 0.0f);
        unsigned long long b6 = __ballot(v1[2] > 0.0f);
        unsigned long long b7 = __ballot(v1[3] > 0.0f);
        int o = count + __popcll(b0 & mlt) + __popcll(b1 & mlt)
                      + __popcll(b2 & mlt) + __popcll(b3 & mlt);
        int c0 = base + (lane << 2);
        if (v0[0] > 0.0f) { if (o < MAXDEG) crow[o] = c0;     o++; }
        if (v0[1] > 0.0f) { if (o < MAXDEG) crow[o] = c0 + 1; o++; }
        if (v0[2] > 0.0f) { if (o < MAXDEG) crow[o] = c0 + 2; o++; }
        if (v0[3] > 0.0f) { if (o < MAXDEG) crow[o] = c0 + 3; o++; }
        count += __popcll(b0) + __popcll(b1) + __popcll(b2) + __popcll(b3);
        o = count + __popcll(b4 & mlt) + __popcll(b5 & mlt)
                  + __popcll(b6 & mlt) + __popcll(b7 & mlt);
        int c1 = base + 256 + (lane << 2);
        if (v1[0] > 0.0f) { if (o < MAXDEG) crow[o] = c1;     o++; }
        if (v1[1] > 0.0f) { if (o < MAXDEG) crow[o] = c1 + 1; o++; }
        if (v1[2] > 0.0f) { if (o < MAXDEG) crow[o] = c1 + 2; o++; }
        if (v1[3] > 0.0f) { if (o < MAXDEG) crow[o] = c1 + 3; o++; }
        count += __popcll(b4) + __popcll(b5) + __popcll(b6) + __popcll(b7);
    }
    if (lane == 0) cnt[row] = count > MAXDEG ? MAXDEG : count;
}

__device__ void csr_quad(int q, const GP& p) {
    const int row = q * 4 + (threadIdx.x >> 6);
    csr_row(p.adj, p.cols, p.cnt, row, threadIdx.x & 63);
}

// ---------------------------------------------------------------------------
// GEMM1 tile: Wh1[64 x 128] fp16 = x(f32->f16) @ W1T col-tile.
// BM=64, BN=128, BK=64; 4 waves (2m x 2n). Epilogue: atomic s1/t1.
// ---------------------------------------------------------------------------
__device__ void gemm1_tile(char* smem, const GP& p, int brow, int bcol) {
    const int LDT = 72;
    _Float16* As = (_Float16*)smem;                  // 64 x 72
    _Float16* Bs = (_Float16*)(smem + 64 * LDT * 2); // 128 x 72
    const int tid = threadIdx.x;
    const int wid = tid >> 6, lane = tid & 63;
    const int wr = (wid >> 1) * 32, wc = (wid & 1) * 64;
    const int sr = tid >> 3, skg = (tid & 7) * 8;

    f32x4 acc[2][4];
    #pragma unroll
    for (int m = 0; m < 2; ++m)
        #pragma unroll
        for (int n = 0; n < 4; ++n) acc[m][n] = f32x4{0.f, 0.f, 0.f, 0.f};

    for (int k0 = 0; k0 < F_IN; k0 += 64) {
        #pragma unroll
        for (int i = 0; i < 2; ++i) {
            int r = sr + i * 32;
            const f32x4* src = (const f32x4*)(p.x + (size_t)(brow + r) * F_IN + k0 + skg);
            f32x4 a0 = src[0];
            f32x4 a1v = src[1];
            f16x8 av;
            #pragma unroll
            for (int j = 0; j < 4; ++j) { av[j] = (_Float16)a0[j]; av[4 + j] = (_Float16)a1v[j]; }
            *(f16x8*)&As[r * LDT + skg] = av;
        }
        #pragma unroll
        for (int i = 0; i < 4; ++i) {
            int r = sr + i * 32;
            *(f16x8*)&Bs[r * LDT + skg] =
                *(const f16x8*)&p.W1T[(size_t)(bcol + r) * F_IN + k0 + skg];
        }
        __syncthreads();
        #pragma unroll
        for (int ks = 0; ks < 2; ++ks) {
            const int kb = ks * 32 + (lane >> 4) * 8;
            f16x8 af[2], bfr[4];
            #pragma unroll
            for (int m = 0; m < 2; ++m)
                af[m] = *(const f16x8*)&As[(wr + m * 16 + (lane & 15)) * LDT + kb];
            #pragma unroll
            for (int n = 0; n < 4; ++n)
                bfr[n] = *(const f16x8*)&Bs[(wc + n * 16 + (lane & 15)) * LDT + kb];
            #pragma unroll
            for (int m = 0; m < 2; ++m)
                #pragma unroll
                for (int n = 0; n < 4; ++n)
                    acc[m][n] = __builtin_amdgcn_mfma_f32_16x16x32_f16(
                        af[m], bfr[n], acc[m][n], 0, 0, 0);
        }
        __syncthreads();
    }
    const int cl = lane & 15;
    float as[4], at[4];
    #pragma unroll
    for (int n = 0; n < 4; ++n) {
        as[n] = p.a1[bcol + wc + n * 16 + cl];
        at[n] = p.a1[F_HID + bcol + wc + n * 16 + cl];
    }
    #pragma unroll
    for (int m = 0; m < 2; ++m) {
        #pragma unroll
        for (int j = 0; j < 4; ++j) {
            float vs = 0.f, vt = 0.f;
            #pragma unroll
            for (int n = 0; n < 4; ++n) { vs += acc[m][n][j] * as[n]; vt += acc[m][n][j] * at[n]; }
            #pragma unroll
            for (int off = 1; off < 16; off <<= 1) {
                vs += __shfl_xor(vs, off);
                vt += __shfl_xor(vt, off);
            }
            if (cl == 0) {
                int row = brow + wr + m * 16 + ((lane >> 4) << 2) + j;
                atomicAdd(p.s1 + row, vs);
                atomicAdd(p.t1 + row, vt);
            }
        }
        #pragma unroll
        for (int n = 0; n < 4; ++n) {
            int row = brow + wr + m * 16 + ((lane >> 4) << 2);
            int col = bcol + wc + n * 16 + cl;
            #pragma unroll
            for (int j = 0; j < 4; ++j)
                p.Wh1[(size_t)(row + j) * F_HID + col] = (_Float16)acc[m][n][j];
        }
    }
}

// ---------------------------------------------------------------------------
// Layer-1 aggregate quad (4 rows): softmax(s1,t1), gather Wh1, ELU,
// write enc f32 (NT) + enc16; epilogue s2/t2 = enc_row . w2s/w2t.
// Per-wave LDS slices only -> no block barrier needed.
// ---------------------------------------------------------------------------
__device__ void agg_l1_quad(int q, char* smem, const GP& p) {
    float (*pS)[64] = (float(*)[64])smem;
    int (*jS)[64] = (int(*)[64])(smem + 1024);
    const int wid = threadIdx.x >> 6, lane = threadIdx.x & 63;
    const int row = q * 4 + wid;
    const int deg = p.cnt[row];
    int j = 0;
    float ev = -1e30f;
    if (lane < deg) {
        j = p.cols[(size_t)row * MAXDEG + lane];
        float z = p.s1[row] + p.t1[j];
        ev = z > 0.0f ? z : ALPHA * z;
    }
    float m = ev;
    #pragma unroll
    for (int off = 32; off > 0; off >>= 1) m = fmaxf(m, __shfl_xor(m, off));
    float ex = (lane < deg) ? __expf(ev - m) : 0.0f;
    float sum = ex;
    #pragma unroll
    for (int off = 32; off > 0; off >>= 1) sum += __shfl_xor(sum, off);
    pS[wid][lane] = ex / sum;
    jS[wid][lane] = j;

    float acc[4] = {};
    const size_t lo = (size_t)lane * 4;
    int d = 0;
    for (; d + 4 <= deg; d += 4) {
        float p0 = pS[wid][d],     p1 = pS[wid][d + 1];
        float p2 = pS[wid][d + 2], p3 = pS[wid][d + 3];
        f16x4 v0 = *(const f16x4*)(p.Wh1 + (size_t)jS[wid][d] * F_HID + lo);
        f16x4 v1 = *(const f16x4*)(p.Wh1 + (size_t)jS[wid][d + 1] * F_HID + lo);
        f16x4 v2 = *(const f16x4*)(p.Wh1 + (size_t)jS[wid][d + 2] * F_HID + lo);
        f16x4 v3 = *(const f16x4*)(p.Wh1 + (size_t)jS[wid][d + 3] * F_HID + lo);
        #pragma unroll
        for (int jj = 0; jj < 4; ++jj)
            acc[jj] += p0 * (float)v0[jj] + p1 * (float)v1[jj]
                     + p2 * (float)v2[jj] + p3 * (float)v3[jj];
    }
    for (; d < deg; ++d) {
        float pd = pS[wid][d];
        f16x4 w = *(const f16x4*)(p.Wh1 + (size_t)jS[wid][d] * F_HID + lo);
        #pragma unroll
        for (int jj = 0; jj < 4; ++jj) acc[jj] += pd * (float)w[jj];
    }
    f32x4 o; f16x4 h;
    #pragma unroll
    for (int jj = 0; jj < 4; ++jj) {
        float v = acc[jj];
        float e = v > 0.0f ? v : (__expf(v) - 1.0f);
        o[jj] = e; h[jj] = (_Float16)e;
    }
    __builtin_nontemporal_store(o, (f32x4*)(p.enc + (size_t)row * F_HID + lo));
    *(f16x4*)(p.enc16 + (size_t)row * F_HID + lo) = h;

    f32x4 ws = *(const f32x4*)(p.w2s + lo);
    f32x4 wt = *(const f32x4*)(p.w2t + lo);
    float ps = 0.f, pt = 0.f;
    #pragma unroll
    for (int jj = 0; jj < 4; ++jj) { ps += o[jj] * ws[jj]; pt += o[jj] * wt[jj]; }
    #pragma unroll
    for (int off = 32; off > 0; off >>= 1) {
        ps += __shfl_xor(ps, off);
        pt += __shfl_xor(pt, off);
    }
    if (lane == 0) { p.s2[row] = ps; p.t2[row] = pt; }
}

// ---------------------------------------------------------------------------
// Layer-2 pre-aggregate quad: softmax(s2,t2), gather enc16, write aggE16.
// ---------------------------------------------------------------------------
__device__ void agg_l2_quad(int q, char* smem, const GP& p) {
    float (*pS)[64] = (float(*)[64])smem;
    int (*jS)[64] = (int(*)[64])(smem + 1024);
    const int wid = threadIdx.x >> 6, lane = threadIdx.x & 63;
    const int row = q * 4 + wid;
    const int deg = p.cnt[row];
    int j = 0;
    float ev = -1e30f;
    if (lane < deg) {
        j = p.cols[(size_t)row * MAXDEG + lane];
        float z = p.s2[row] + p.t2[j];
        ev = z > 0.0f ? z : ALPHA * z;
    }
    float m = ev;
    #pragma unroll
    for (int off = 32; off > 0; off >>= 1) m = fmaxf(m, __shfl_xor(m, off));
    float ex = (lane < deg) ? __expf(ev - m) : 0.0f;
    float sum = ex;
    #pragma unroll
    for (int off = 32; off > 0; off >>= 1) sum += __shfl_xor(sum, off);
    pS[wid][lane] = ex / sum;
    jS[wid][lane] = j;

    float acc[4] = {};
    const size_t lo = (size_t)lane * 4;
    int d = 0;
    for (; d + 4 <= deg; d += 4) {
        float p0 = pS[wid][d],     p1 = pS[wid][d + 1];
        float p2 = pS[wid][d + 2], p3 = pS[wid][d + 3];
        f16x4 v0 = *(const f16x4*)(p.enc16 + (size_t)jS[wid][d] * F_HID + lo);
        f16x4 v1 = *(const f16x4*)(p.enc16 + (size_t)jS[wid][d + 1] * F_HID + lo);
        f16x4 v2 = *(const f16x4*)(p.enc16 + (size_t)jS[wid][d + 2] * F_HID + lo);
        f16x4 v3 = *(const f16x4*)(p.enc16 + (size_t)jS[wid][d + 3] * F_HID + lo);
        #pragma unroll
        for (int jj = 0; jj < 4; ++jj)
            acc[jj] += p0 * (float)v0[jj] + p1 * (float)v1[jj]
                     + p2 * (float)v2[jj] + p3 * (float)v3[jj];
    }
    for (; d < deg; ++d) {
        float pd = pS[wid][d];
        f16x4 w = *(const f16x4*)(p.enc16 + (size_t)jS[wid][d] * F_HID + lo);
        #pragma unroll
        for (int jj = 0; jj < 4; ++jj) acc[jj] += pd * (float)w[jj];
    }
    f16x4 h;
    #pragma unroll
    for (int jj = 0; jj < 4; ++jj) h[jj] = (_Float16)acc[jj];
    *(f16x4*)(p.aggE16 + (size_t)row * F_HID + lo) = h;
}

// ---------------------------------------------------------------------------
// GEMM2e tile: dec[128 x 64] f32 = elu( aggE16 @ W2 ). BK=64 restaged.
// tile -> brow = (tile>>3)*128, bcol = (tile&7)*64.
// ---------------------------------------------------------------------------
__device__ void gemm2e_tile(int tile, char* smem, const GP& p) {
    const int LDT = 72;
    _Float16* As = (_Float16*)smem;                   // 128 x 72
    _Float16* Bs = (_Float16*)(smem + 128 * LDT * 2); // 64 x 72
    const int tid = threadIdx.x;
    const int wid = tid >> 6, lane = tid & 63;
    const int brow = (tile >> 3) * 128;
    const int bcol = (tile & 7) * 64;
    const int wr = (wid >> 1) * 64, wc = (wid & 1) * 32;

    f32x4 acc[4][2];
    #pragma unroll
    for (int m = 0; m < 4; ++m)
        #pragma unroll
        for (int n = 0; n < 2; ++n) acc[m][n] = f32x4{0.f, 0.f, 0.f, 0.f};

    for (int k0 = 0; k0 < F_HID; k0 += 64) {
        #pragma unroll
        for (int i = 0; i < 4; ++i) {
            int id = tid + i * 256;
            int r = id >> 3, kc = (id & 7) * 8;
            *(f16x8*)&As[r * LDT + kc] =
                *(const f16x8*)&p.aggE16[(size_t)(brow + r) * F_HID + k0 + kc];
        }
        #pragma unroll
        for (int i = 0; i < 2; ++i) {
            int id = tid + i * 256;
            int r = id >> 3, kc = (id & 7) * 8;
            *(f16x8*)&Bs[r * LDT + kc] =
                *(const f16x8*)&p.W2T[(size_t)(bcol + r) * F_HID + k0 + kc];
        }
        __syncthreads();
        #pragma unroll
        for (int ks = 0; ks < 2; ++ks) {
            const int kb = ks * 32 + (lane >> 4) * 8;
            f16x8 af[4], bfr[2];
            #pragma unroll
            for (int m = 0; m < 4; ++m)
                af[m] = *(const f16x8*)&As[(wr + m * 16 + (lane & 15)) * LDT + kb];
            #pragma unroll
            for (int n = 0; n < 2; ++n)
                bfr[n] = *(const f16x8*)&Bs[(wc + n * 16 + (lane & 15)) * LDT + kb];
            #pragma unroll
            for (int m = 0; m < 4; ++m)
                #pragma unroll
                for (int n = 0; n < 2; ++n)
                    acc[m][n] = __builtin_amdgcn_mfma_f32_16x16x32_f16(
                        af[m], bfr[n], acc[m][n], 0, 0, 0);
        }
        __syncthreads();
    }
    #pragma unroll
    for (int m = 0; m < 4; ++m)
        #pragma unroll
        for (int n = 0; n < 2; ++n) {
            int row = brow + wr + m * 16 + ((lane >> 4) << 2);
            int col = bcol + wc + n * 16 + (lane & 15);
            #pragma unroll
            for (int j = 0; j < 4; ++j) {
                float v = acc[m][n][j];
                float e = v > 0.0f ? v : (__expf(v) - 1.0f);
                __builtin_nontemporal_store(e, &p.dec[(size_t)(row + j) * F_IN + col]);
            }
        }
}

// ---------------------------------------------------------------------------
// Cooperative mega-kernel: 7 phases, csr stream pipelined under prep/gemm1/
// agg_l1; l2 gemm overlapped with second half of agg_l2pre.
// ---------------------------------------------------------------------------
__global__ __launch_bounds__(256, 4) void gat_mega(GP p) {
    __shared__ __align__(16) char smem[SMEM_BYTES];
    cg::grid_group grid = cg::this_grid();
    const int bid = blockIdx.x;
    const int tid = threadIdx.x;

    // P0: prep (blocks 0..259) || csr quads 0..763 (blocks 260..1023)
    {
        int gid = bid * 256 + tid;
        if (gid < 2 * N_NODES) p.s1[gid] = 0.0f;     // s1,t1 contiguous
        if (bid < 260) prep_job(bid, smem, p);
        else csr_quad(bid - 260, p);                  // 764 quads, one each
    }
    grid.sync();
    // P1: gemm1 (256 tiles) || csr quads 764..1531
    if (bid < 256) gemm1_tile(smem, p, (bid & 127) * 64, (bid >> 7) * 128);
    else csr_quad(764 + (bid - 256), p);              // 768 quads, one each
    grid.sync();
    // P2: agg_l1 rows 0..3055 || csr quads 1532..2047
    if (bid < 764) agg_l1_quad(bid, smem, p);
    else {
        for (int q = 1532 + (bid - 764); q < 2048; q += 260) csr_quad(q, p);
    }
    grid.sync();
    // P3: agg_l1 rows 3056..8191
    for (int q = 764 + bid; q < 2048; q += GRID_COOP) agg_l1_quad(q, smem, p);
    grid.sync();
    // P4: agg_l2pre rows 0..4095
    agg_l2_quad(bid, smem, p);
    grid.sync();
    // P5: gemm2e rows 0..4095 (tiles 0..255) || agg_l2pre rows 4096..8191
    if (bid < 256) gemm2e_tile(bid, smem, p);
    else {
        for (int q = 1024 + (bid - 256); q < 2048; q += 768) agg_l2_quad(q, smem, p);
    }
    grid.sync();
    // P6: gemm2e rows 4096..8191 (tiles 256..511)
    if (bid < 256) gemm2e_tile(256 + bid, smem, p);
}

// ---------------------------------------------------------------------------
// Fallback path (R9 structure) in case cooperative launch is unavailable.
// ---------------------------------------------------------------------------
__global__ __launch_bounds__(256) void k_prep(GP p) {
    __shared__ __align__(16) char smem[SMEM_BYTES];
    int gid = blockIdx.x * 256 + threadIdx.x;
    if (gid < 2 * N_NODES) p.s1[gid] = 0.0f;
    if (blockIdx.x < 260) prep_job(blockIdx.x, smem, p);
}
__global__ __launch_bounds__(256) void k_csr_gemm1(GP p) {
    __shared__ __align__(16) char smem[SMEM_BYTES];
    if (blockIdx.x < 256)
        gemm1_tile(smem, p, (blockIdx.x & 127) * 64, (blockIdx.x >> 7) * 128);
    else
        csr_quad(blockIdx.x - 256, p);
}
__global__ __launch_bounds__(256) void k_agg1(GP p) {
    __shared__ __align__(16) char smem[SMEM_BYTES];
    agg_l1_quad(blockIdx.x, smem, p);
}
__global__ __launch_bounds__(256) void k_agg2(GP p) {
    __shared__ __align__(16) char smem[SMEM_BYTES];
    agg_l2_quad(blockIdx.x, smem, p);
}
__global__ __launch_bounds__(256) void k_gemm2(GP p) {
    __shared__ __align__(16) char smem[SMEM_BYTES];
    gemm2e_tile(blockIdx.x, smem, p);
}

// ---------------------------------------------------------------------------
extern "C" void kernel_launch(void* const* d_in, const int* in_sizes, int n_in,
                              void* d_out, int out_size, void* d_ws, size_t ws_size,
                              hipStream_t stream) {
    (void)in_sizes; (void)n_in; (void)out_size; (void)ws_size;
    float* dec = (float*)d_out;                           // [8192, 512] f32
    float* enc = dec + (size_t)N_NODES * F_IN;            // [8192, 256] f32

    int*      cols   = (int*)d_ws;                        // 8192*64
    int*      cnt    = cols + (size_t)N_NODES * MAXDEG;   // 8192
    float*    s1     = (float*)(cnt + N_NODES);           // 8192
    float*    t1     = s1 + N_NODES;                      // 8192
    float*    s2     = t1 + N_NODES;                      // 8192
    float*    t2     = s2 + N_NODES;                      // 8192
    float*    w2s    = t2 + N_NODES;                      // 256
    float*    w2t    = w2s + F_HID;                       // 256
    _Float16* Wh1    = (_Float16*)(w2t + F_HID);          // 8192*256 fp16
    _Float16* enc16  = Wh1 + (size_t)N_NODES * F_HID;     // 8192*256 fp16
    _Float16* aggE16 = enc16 + (size_t)N_NODES * F_HID;   // 8192*256 fp16
    _Float16* W1T    = aggE16 + (size_t)N_NODES * F_HID;  // 256*512 fp16
    _Float16* W2T    = W1T + (size_t)F_HID * F_IN;        // 512*256 fp16

    GP p;
    p.x = (const float*)d_in[0]; p.adj = (const float*)d_in[1];
    p.W1 = (const float*)d_in[2]; p.a1 = (const float*)d_in[3];
    p.W2 = (const float*)d_in[4]; p.a2 = (const float*)d_in[5];
    p.dec = dec; p.enc = enc; p.cols = cols; p.cnt = cnt;
    p.s1 = s1; p.t1 = t1; p.s2 = s2; p.t2 = t2; p.w2s = w2s; p.w2t = w2t;
    p.Wh1 = Wh1; p.enc16 = enc16; p.aggE16 = aggE16; p.W1T = W1T; p.W2T = W2T;

    void* kargs[] = { (void*)&p };
    hipError_t err = hipLaunchCooperativeKernel((const void*)gat_mega,
                                                dim3(GRID_COOP), dim3(256),
                                                kargs, 0, stream);
    if (err != hipSuccess) {
        (void)hipGetLastError();   // clear sticky error, use fallback pipeline
        k_prep<<<260, 256, 0, stream>>>(p);
        k_csr_gemm1<<<2304, 256, 0, stream>>>(p);
        k_agg1<<<2048, 256, 0, stream>>>(p);
        k_agg2<<<2048, 256, 0, stream>>>(p);
        k_gemm2<<<512, 256, 0, stream>>>(p);
    }
}

// Round 11
// 108.758 us; speedup vs baseline: 7.5110x; 7.5110x over previous
//
#include <hip/hip_runtime.h>
#include <hip/hip_bf16.h>

#define N_NODES 8192
#define F_IN    512
#define F_HID   256
#define ALPHA   0.2f
#define MAXDEG  64

using f32x4 = __attribute__((ext_vector_type(4))) float;
using f16x8 = __attribute__((ext_vector_type(8))) _Float16;
using f16x4 = __attribute__((ext_vector_type(4))) _Float16;

// ---------------------------------------------------------------------------
// Kernel 1 (prep): W1T/W2T fp16 transposes, w2s/w2t = W2 @ a2 halves,
// zero s1/t1 (atomic targets).
// ---------------------------------------------------------------------------
__global__ void prep_kernel(const float* __restrict__ W1, const float* __restrict__ W2,
                            _Float16* __restrict__ W1T, _Float16* __restrict__ W2T,
                            const float* __restrict__ a2,
                            float* __restrict__ w2s, float* __restrict__ w2t,
                            float* __restrict__ stz) {
    const int tid = threadIdx.x;
    int gid = blockIdx.x * 256 + tid;
    if (gid < 2 * N_NODES) stz[gid] = 0.0f;   // zero s1,t1

    if (blockIdx.x >= 256) {
        const int r = (blockIdx.x - 256) * 64 + (tid >> 2);   // 64 rows/block
        const int q = tid & 3;
        float ss = 0.f, tt = 0.f;
        for (int n = q * 4; n < F_IN; n += 16) {
            f32x4 w  = *(const f32x4*)&W2[(size_t)r * F_IN + n];
            f32x4 as = *(const f32x4*)&a2[n];
            f32x4 at = *(const f32x4*)&a2[F_IN + n];
            #pragma unroll
            for (int j = 0; j < 4; ++j) { ss += w[j] * as[j]; tt += w[j] * at[j]; }
        }
        ss += __shfl_xor(ss, 1); ss += __shfl_xor(ss, 2);
        tt += __shfl_xor(tt, 1); tt += __shfl_xor(tt, 2);
        if (q == 0) { w2s[r] = ss; w2t[r] = tt; }
        return;
    }

    int t = blockIdx.x;
    const float* W; _Float16* WT; int K, N, kt, nt;
    if (t < 128) { W = W1; WT = W1T; K = 512; N = 256; kt = t & 15; nt = t >> 4; }
    else { t -= 128; W = W2; WT = W2T; K = 256; N = 512; kt = t & 7; nt = t >> 3; }
    __shared__ float Ws[32][33];
    const int tx = tid & 31, ty = tid >> 5;  // 32 x 8
    #pragma unroll
    for (int i = 0; i < 4; ++i)
        Ws[ty + 8 * i][tx] = W[(size_t)(kt * 32 + ty + 8 * i) * N + nt * 32 + tx];
    __syncthreads();
    #pragma unroll
    for (int i = 0; i < 4; ++i)
        WT[(size_t)(nt * 32 + ty + 8 * i) * K + kt * 32 + tx] = (_Float16)Ws[tx][ty + 8 * i];
}

// ---------------------------------------------------------------------------
// CSR row scan (device): one wave per adjacency row.
// ---------------------------------------------------------------------------
__device__ inline void csr_row(const float* __restrict__ adj, int* __restrict__ cols,
                               int* __restrict__ cnt, int row, int lane) {
    const f32x4* arow = (const f32x4*)(adj + (size_t)row * N_NODES);
    int* crow = cols + (size_t)row * MAXDEG;
    int count = 0;
    const unsigned long long mlt = (1ULL << lane) - 1ULL;
    for (int base = 0; base < N_NODES; base += 512) {
        f32x4 v0 = __builtin_nontemporal_load(&arow[(base >> 2) + lane]);
        f32x4 v1 = __builtin_nontemporal_load(&arow[(base >> 2) + 64 + lane]);
        unsigned long long b0 = __ballot(v0[0] > 0.0f);
        unsigned long long b1 = __ballot(v0[1] > 0.0f);
        unsigned long long b2 = __ballot(v0[2] > 0.0f);
        unsigned long long b3 = __ballot(v0[3] > 0.0f);
        unsigned long long b4 = __ballot(v1[0] > 0.0f);
        unsigned long long b5 = __ballot(v1[1] > 0.0f);
        unsigned long long b6 = __ballot(v1[2] > 0.0f);
        unsigned long long b7 = __ballot(v1[3] > 0.0f);
        int o = count + __popcll(b0 & mlt) + __popcll(b1 & mlt)
                      + __popcll(b2 & mlt) + __popcll(b3 & mlt);
        int c0 = base + (lane << 2);
        if (v0[0] > 0.0f) { if (o < MAXDEG) crow[o] = c0;     o++; }
        if (v0[1] > 0.0f) { if (o < MAXDEG) crow[o] = c0 + 1; o++; }
        if (v0[2] > 0.0f) { if (o < MAXDEG) crow[o] = c0 + 2; o++; }
        if (v0[3] > 0.0f) { if (o < MAXDEG) crow[o] = c0 + 3; o++; }
        count += __popcll(b0) + __popcll(b1) + __popcll(b2) + __popcll(b3);
        o = count + __popcll(b4 & mlt) + __popcll(b5 & mlt)
                  + __popcll(b6 & mlt) + __popcll(b7 & mlt);
        int c1 = base + 256 + (lane << 2);
        if (v1[0] > 0.0f) { if (o < MAXDEG) crow[o] = c1;     o++; }
        if (v1[1] > 0.0f) { if (o < MAXDEG) crow[o] = c1 + 1; o++; }
        if (v1[2] > 0.0f) { if (o < MAXDEG) crow[o] = c1 + 2; o++; }
        if (v1[3] > 0.0f) { if (o < MAXDEG) crow[o] = c1 + 3; o++; }
        count += __popcll(b4) + __popcll(b5) + __popcll(b6) + __popcll(b7);
    }
    if (lane == 0) cnt[row] = count > MAXDEG ? MAXDEG : count;
}

// ---------------------------------------------------------------------------
// GEMM1 tile (device): Wh1[64 x 128] fp16 = x(f32->f16) @ W1T col-tile.
// BM=64, BN=128, BK=64; 4 waves (2m x 2n). Epilogue: atomic s1/t1.
// ---------------------------------------------------------------------------
__device__ inline void gemm1_tile(const float* __restrict__ x,
                                  const _Float16* __restrict__ W1T,
                                  _Float16* __restrict__ Wh1,
                                  const float* __restrict__ a1,
                                  float* __restrict__ s1, float* __restrict__ t1,
                                  int brow, int bcol) {
    const int LDT = 72;
    __shared__ _Float16 As[64 * LDT];
    __shared__ _Float16 Bs[128 * LDT];
    const int tid = threadIdx.x;
    const int wid = tid >> 6, lane = tid & 63;
    const int wr = (wid >> 1) * 32, wc = (wid & 1) * 64;
    const int sr = tid >> 3, skg = (tid & 7) * 8;

    f32x4 acc[2][4];
    #pragma unroll
    for (int m = 0; m < 2; ++m)
        #pragma unroll
        for (int n = 0; n < 4; ++n) acc[m][n] = f32x4{0.f, 0.f, 0.f, 0.f};

    for (int k0 = 0; k0 < F_IN; k0 += 64) {
        #pragma unroll
        for (int i = 0; i < 2; ++i) {
            int r = sr + i * 32;
            const f32x4* src = (const f32x4*)(x + (size_t)(brow + r) * F_IN + k0 + skg);
            f32x4 a0 = src[0];
            f32x4 a1v = src[1];
            f16x8 av;
            #pragma unroll
            for (int j = 0; j < 4; ++j) { av[j] = (_Float16)a0[j]; av[4 + j] = (_Float16)a1v[j]; }
            *(f16x8*)&As[r * LDT + skg] = av;
        }
        #pragma unroll
        for (int i = 0; i < 4; ++i) {
            int r = sr + i * 32;
            *(f16x8*)&Bs[r * LDT + skg] =
                *(const f16x8*)&W1T[(size_t)(bcol + r) * F_IN + k0 + skg];
        }
        __syncthreads();
        #pragma unroll
        for (int ks = 0; ks < 2; ++ks) {
            const int kb = ks * 32 + (lane >> 4) * 8;
            f16x8 af[2], bfr[4];
            #pragma unroll
            for (int m = 0; m < 2; ++m)
                af[m] = *(const f16x8*)&As[(wr + m * 16 + (lane & 15)) * LDT + kb];
            #pragma unroll
            for (int n = 0; n < 4; ++n)
                bfr[n] = *(const f16x8*)&Bs[(wc + n * 16 + (lane & 15)) * LDT + kb];
            #pragma unroll
            for (int m = 0; m < 2; ++m)
                #pragma unroll
                for (int n = 0; n < 4; ++n)
                    acc[m][n] = __builtin_amdgcn_mfma_f32_16x16x32_f16(
                        af[m], bfr[n], acc[m][n], 0, 0, 0);
        }
        __syncthreads();
    }
    const int cl = lane & 15;
    float as[4], at[4];
    #pragma unroll
    for (int n = 0; n < 4; ++n) {
        as[n] = a1[bcol + wc + n * 16 + cl];
        at[n] = a1[F_HID + bcol + wc + n * 16 + cl];
    }
    #pragma unroll
    for (int m = 0; m < 2; ++m) {
        #pragma unroll
        for (int j = 0; j < 4; ++j) {
            float vs = 0.f, vt = 0.f;
            #pragma unroll
            for (int n = 0; n < 4; ++n) { vs += acc[m][n][j] * as[n]; vt += acc[m][n][j] * at[n]; }
            #pragma unroll
            for (int off = 1; off < 16; off <<= 1) {
                vs += __shfl_xor(vs, off);
                vt += __shfl_xor(vt, off);
            }
            if (cl == 0) {
                int row = brow + wr + m * 16 + ((lane >> 4) << 2) + j;
                atomicAdd(s1 + row, vs);
                atomicAdd(t1 + row, vt);
            }
        }
        #pragma unroll
        for (int n = 0; n < 4; ++n) {
            int row = brow + wr + m * 16 + ((lane >> 4) << 2);
            int col = bcol + wc + n * 16 + cl;
            #pragma unroll
            for (int j = 0; j < 4; ++j)
                Wh1[(size_t)(row + j) * F_HID + col] = (_Float16)acc[m][n][j];
        }
    }
}

// ---------------------------------------------------------------------------
// Kernel 2: csr scan (ALL rows) co-scheduled with GEMM1 (low blockIds).
// ---------------------------------------------------------------------------
__global__ __launch_bounds__(256)
void csr_and_gemm1(const float* __restrict__ adj, int* __restrict__ cols,
                   int* __restrict__ cnt, const float* __restrict__ x,
                   const _Float16* __restrict__ W1T, _Float16* __restrict__ Wh1,
                   const float* __restrict__ a1,
                   float* __restrict__ s1, float* __restrict__ t1) {
    const int bid = blockIdx.x;
    if (bid < 256) {
        gemm1_tile(x, W1T, Wh1, a1, s1, t1, (bid & 127) * 64, (bid >> 7) * 128);
    } else {
        const int q = bid - 256;                        // quad in [0, 2048)
        const int row = q * 4 + (threadIdx.x >> 6);
        csr_row(adj, cols, cnt, row, threadIdx.x & 63);
    }
}

// ---------------------------------------------------------------------------
// Kernel 3: layer-1 aggregate, paired-neighbor gather (16B/lane):
// lanes 0-31 fetch neighbor d, lanes 32-63 fetch d+1; combine via shfl_xor(32).
// ELU, write enc f32 (NT) + enc16; epilogue s2/t2 = enc_row . w2s/w2t.
// ---------------------------------------------------------------------------
__global__ __launch_bounds__(256)
void aggregate_l1(const _Float16* __restrict__ Wh,
                  const int* __restrict__ cols, const int* __restrict__ cnt,
                  const float* __restrict__ s, const float* __restrict__ t,
                  const float* __restrict__ w2s, const float* __restrict__ w2t,
                  float* __restrict__ enc, _Float16* __restrict__ enc16,
                  float* __restrict__ s2, float* __restrict__ t2) {
    const int wid = threadIdx.x >> 6, lane = threadIdx.x & 63;
    const int row = blockIdx.x * 4 + wid;
    const int deg = cnt[row];
    const int half = lane >> 5, fl = lane & 31;

    int j = 0;
    float ev = -1e30f;
    if (lane < deg) {
        j = cols[(size_t)row * MAXDEG + lane];
        float z = s[row] + t[j];
        ev = z > 0.0f ? z : ALPHA * z;
    }
    float m = ev;
    #pragma unroll
    for (int off = 32; off > 0; off >>= 1) m = fmaxf(m, __shfl_xor(m, off));
    float ex = (lane < deg) ? __expf(ev - m) : 0.0f;
    float sum = ex;
    #pragma unroll
    for (int off = 32; off > 0; off >>= 1) sum += __shfl_xor(sum, off);
    const float pp = ex / sum;

    float acc[8] = {};
    const size_t fo = (size_t)fl * 8;
    int d = 0;
    for (; d + 2 <= deg; d += 2) {
        const int dd = d + half;
        float pd = __shfl(pp, dd);
        int jd = __shfl(j, dd);
        f16x8 v = *(const f16x8*)(Wh + (size_t)jd * F_HID + fo);
        #pragma unroll
        for (int k = 0; k < 8; ++k) acc[k] += pd * (float)v[k];
    }
    if (deg & 1) {
        const int dd = deg - 1;
        float pd = __shfl(pp, dd);
        int jd = __shfl(j, dd);
        if (half == 0) {
            f16x8 v = *(const f16x8*)(Wh + (size_t)jd * F_HID + fo);
            #pragma unroll
            for (int k = 0; k < 8; ++k) acc[k] += pd * (float)v[k];
        }
    }
    #pragma unroll
    for (int k = 0; k < 8; ++k) acc[k] += __shfl_xor(acc[k], 32);

    float ps = 0.f, pt = 0.f;
    if (half == 0) {
        f32x4 o0, o1; f16x8 h;
        #pragma unroll
        for (int k = 0; k < 8; ++k) {
            float v = acc[k];
            float e = v > 0.0f ? v : (__expf(v) - 1.0f);
            if (k < 4) o0[k] = e; else o1[k - 4] = e;
            h[k] = (_Float16)e;
            acc[k] = e;
        }
        __builtin_nontemporal_store(o0, (f32x4*)(enc + (size_t)row * F_HID + fo));
        __builtin_nontemporal_store(o1, (f32x4*)(enc + (size_t)row * F_HID + fo + 4));
        *(f16x8*)(enc16 + (size_t)row * F_HID + fo) = h;

        f32x4 ws0 = *(const f32x4*)(w2s + fo), ws1 = *(const f32x4*)(w2s + fo + 4);
        f32x4 wt0 = *(const f32x4*)(w2t + fo), wt1 = *(const f32x4*)(w2t + fo + 4);
        #pragma unroll
        for (int k = 0; k < 4; ++k) {
            ps += acc[k] * ws0[k] + acc[k + 4] * ws1[k];
            pt += acc[k] * wt0[k] + acc[k + 4] * wt1[k];
        }
    }
    #pragma unroll
    for (int off = 16; off > 0; off >>= 1) {
        ps += __shfl_xor(ps, off);
        pt += __shfl_xor(pt, off);
    }
    if (lane == 0) { s2[row] = ps; t2[row] = pt; }
}

// ---------------------------------------------------------------------------
// Kernel 4: fused layer-2. 16-row slab per block: softmax(s2,t2) + paired
// gather of enc16 -> aggE in LDS (MFMA A operand) -> @ W2T -> elu -> dec.
// ---------------------------------------------------------------------------
__global__ __launch_bounds__(256)
void l2_fused(const _Float16* __restrict__ enc16, const _Float16* __restrict__ W2T,
              const int* __restrict__ cols, const int* __restrict__ cnt,
              const float* __restrict__ s2, const float* __restrict__ t2,
              float* __restrict__ dec) {
    const int LDA = 264, LDB = 264;
    __shared__ _Float16 aggE[16 * LDA];    // 8.4 KB
    __shared__ _Float16 Bs[64 * LDB];      // 33.8 KB
    const int base = blockIdx.x * 16;
    const int wid = threadIdx.x >> 6, lane = threadIdx.x & 63;
    const int half = lane >> 5, fl = lane & 31;

    // phase A: wave wid aggregates rows base+wid*4 .. +3 (paired gather)
    for (int rr = 0; rr < 4; ++rr) {
        const int row = base + wid * 4 + rr;
        const int deg = cnt[row];
        const float sI = s2[row];
        int j = 0;
        float ev = -1e30f;
        if (lane < deg) {
            j = cols[(size_t)row * MAXDEG + lane];
            float z = sI + t2[j];
            ev = z > 0.0f ? z : ALPHA * z;
        }
        float m = ev;
        #pragma unroll
        for (int off = 32; off > 0; off >>= 1) m = fmaxf(m, __shfl_xor(m, off));
        float ex = (lane < deg) ? __expf(ev - m) : 0.0f;
        float sum = ex;
        #pragma unroll
        for (int off = 32; off > 0; off >>= 1) sum += __shfl_xor(sum, off);
        const float pp = ex / sum;

        float acc[8] = {};
        const size_t fo = (size_t)fl * 8;
        int d = 0;
        for (; d + 2 <= deg; d += 2) {
            const int dd = d + half;
            float pd = __shfl(pp, dd);
            int jd = __shfl(j, dd);
            f16x8 v = *(const f16x8*)(enc16 + (size_t)jd * F_HID + fo);
            #pragma unroll
            for (int k = 0; k < 8; ++k) acc[k] += pd * (float)v[k];
        }
        if (deg & 1) {
            const int dd = deg - 1;
            float pd = __shfl(pp, dd);
            int jd = __shfl(j, dd);
            if (half == 0) {
                f16x8 v = *(const f16x8*)(enc16 + (size_t)jd * F_HID + fo);
                #pragma unroll
                for (int k = 0; k < 8; ++k) acc[k] += pd * (float)v[k];
            }
        }
        #pragma unroll
        for (int k = 0; k < 8; ++k) acc[k] += __shfl_xor(acc[k], 32);
        if (half == 0) {
            f16x8 h;
            #pragma unroll
            for (int k = 0; k < 8; ++k) h[k] = (_Float16)acc[k];
            *(f16x8*)&aggE[(wid * 4 + rr) * LDA + fl * 8] = h;
        }
    }
    __syncthreads();

    // hoist A fragments: row = lane&15, 8 k-frags of 32
    f16x8 af[8];
    #pragma unroll
    for (int kf = 0; kf < 8; ++kf)
        af[kf] = *(const f16x8*)&aggE[(lane & 15) * LDA + kf * 32 + (lane >> 4) * 8];

    // phase B: 8 col-tiles of 64; wave wid covers 16 cols of each tile
    for (int ct = 0; ct < 8; ++ct) {
        #pragma unroll
        for (int i = 0; i < 8; ++i) {
            int idx = threadIdx.x + i * 256;
            int c = idx >> 5, kg = (idx & 31) * 8;
            *(f16x8*)&Bs[c * LDB + kg] =
                *(const f16x8*)&W2T[(size_t)(ct * 64 + c) * F_HID + kg];
        }
        __syncthreads();
        f32x4 oacc = f32x4{0.f, 0.f, 0.f, 0.f};
        #pragma unroll
        for (int kf = 0; kf < 8; ++kf) {
            f16x8 bf = *(const f16x8*)&Bs[(wid * 16 + (lane & 15)) * LDB
                                          + kf * 32 + (lane >> 4) * 8];
            oacc = __builtin_amdgcn_mfma_f32_16x16x32_f16(af[kf], bf, oacc, 0, 0, 0);
        }
        const int col = ct * 64 + wid * 16 + (lane & 15);
        const int row0 = base + ((lane >> 4) << 2);
        #pragma unroll
        for (int jj = 0; jj < 4; ++jj) {
            float v = oacc[jj];
            float e = v > 0.0f ? v : (__expf(v) - 1.0f);
            __builtin_nontemporal_store(e, &dec[(size_t)(row0 + jj) * F_IN + col]);
        }
        __syncthreads();
    }
}

// ---------------------------------------------------------------------------
extern "C" void kernel_launch(void* const* d_in, const int* in_sizes, int n_in,
                              void* d_out, int out_size, void* d_ws, size_t ws_size,
                              hipStream_t stream) {
    (void)in_sizes; (void)n_in; (void)out_size; (void)ws_size;
    const float* x   = (const float*)d_in[0];
    const float* adj = (const float*)d_in[1];
    const float* W1  = (const float*)d_in[2];
    const float* a1  = (const float*)d_in[3];
    const float* W2  = (const float*)d_in[4];
    const float* a2  = (const float*)d_in[5];

    float* dec = (float*)d_out;                           // [8192, 512] f32
    float* enc = dec + (size_t)N_NODES * F_IN;            // [8192, 256] f32

    int*      cols  = (int*)d_ws;                         // 8192*64
    int*      cnt   = cols + (size_t)N_NODES * MAXDEG;    // 8192
    float*    s1    = (float*)(cnt + N_NODES);            // 8192
    float*    t1    = s1 + N_NODES;                       // 8192
    float*    s2    = t1 + N_NODES;                       // 8192
    float*    t2    = s2 + N_NODES;                       // 8192
    float*    w2s   = t2 + N_NODES;                       // 256
    float*    w2t   = w2s + F_HID;                        // 256
    _Float16* Wh1   = (_Float16*)(w2t + F_HID);           // 8192*256 fp16
    _Float16* enc16 = Wh1 + (size_t)N_NODES * F_HID;      // 8192*256 fp16
    _Float16* W1T   = enc16 + (size_t)N_NODES * F_HID;    // 256*512 fp16
    _Float16* W2T   = W1T + (size_t)F_HID * F_IN;         // 512*256 fp16

    // 1. prep: transposes, w2s/w2t, zero s1/t1
    prep_kernel<<<260, 256, 0, stream>>>(W1, W2, W1T, W2T, a2, w2s, w2t, s1);

    // 2. csr scan (all rows) overlapped with layer-1 GEMM (BN=128, low bids)
    csr_and_gemm1<<<2304, 256, 0, stream>>>(adj, cols, cnt, x, W1T, Wh1, a1, s1, t1);

    // 3. layer-1 attention -> enc, enc16; epilogue s2/t2
    aggregate_l1<<<N_NODES / 4, 256, 0, stream>>>(Wh1, cols, cnt, s1, t1,
                                                  w2s, w2t, enc, enc16, s2, t2);

    // 4. fused layer-2: aggregate enc16 (LDS) -> @W2 -> elu -> dec
    l2_fused<<<N_NODES / 16, 256, 0, stream>>>(enc16, W2T, cols, cnt, s2, t2, dec);
}

// Round 12
// 99.247 us; speedup vs baseline: 8.2309x; 1.0958x over previous
//
#include <hip/hip_runtime.h>
#include <hip/hip_bf16.h>

#define N_NODES 8192
#define F_IN    512
#define F_HID   256
#define ALPHA   0.2f
#define MAXDEG  64

using f32x4 = __attribute__((ext_vector_type(4))) float;
using f16x8 = __attribute__((ext_vector_type(8))) _Float16;
using f16x4 = __attribute__((ext_vector_type(4))) _Float16;

// ---------------------------------------------------------------------------
// CSR row scan (device): one wave per adjacency row.
// ---------------------------------------------------------------------------
__device__ inline void csr_row(const float* __restrict__ adj, int* __restrict__ cols,
                               int* __restrict__ cnt, int row, int lane) {
    const f32x4* arow = (const f32x4*)(adj + (size_t)row * N_NODES);
    int* crow = cols + (size_t)row * MAXDEG;
    int count = 0;
    const unsigned long long mlt = (1ULL << lane) - 1ULL;
    for (int base = 0; base < N_NODES; base += 512) {
        f32x4 v0 = __builtin_nontemporal_load(&arow[(base >> 2) + lane]);
        f32x4 v1 = __builtin_nontemporal_load(&arow[(base >> 2) + 64 + lane]);
        unsigned long long b0 = __ballot(v0[0] > 0.0f);
        unsigned long long b1 = __ballot(v0[1] > 0.0f);
        unsigned long long b2 = __ballot(v0[2] > 0.0f);
        unsigned long long b3 = __ballot(v0[3] > 0.0f);
        unsigned long long b4 = __ballot(v1[0] > 0.0f);
        unsigned long long b5 = __ballot(v1[1] > 0.0f);
        unsigned long long b6 = __ballot(v1[2] > 0.0f);
        unsigned long long b7 = __ballot(v1[3] > 0.0f);
        int o = count + __popcll(b0 & mlt) + __popcll(b1 & mlt)
                      + __popcll(b2 & mlt) + __popcll(b3 & mlt);
        int c0 = base + (lane << 2);
        if (v0[0] > 0.0f) { if (o < MAXDEG) crow[o] = c0;     o++; }
        if (v0[1] > 0.0f) { if (o < MAXDEG) crow[o] = c0 + 1; o++; }
        if (v0[2] > 0.0f) { if (o < MAXDEG) crow[o] = c0 + 2; o++; }
        if (v0[3] > 0.0f) { if (o < MAXDEG) crow[o] = c0 + 3; o++; }
        count += __popcll(b0) + __popcll(b1) + __popcll(b2) + __popcll(b3);
        o = count + __popcll(b4 & mlt) + __popcll(b5 & mlt)
                  + __popcll(b6 & mlt) + __popcll(b7 & mlt);
        int c1 = base + 256 + (lane << 2);
        if (v1[0] > 0.0f) { if (o < MAXDEG) crow[o] = c1;     o++; }
        if (v1[1] > 0.0f) { if (o < MAXDEG) crow[o] = c1 + 1; o++; }
        if (v1[2] > 0.0f) { if (o < MAXDEG) crow[o] = c1 + 2; o++; }
        if (v1[3] > 0.0f) { if (o < MAXDEG) crow[o] = c1 + 3; o++; }
        count += __popcll(b4) + __popcll(b5) + __popcll(b6) + __popcll(b7);
    }
    if (lane == 0) cnt[row] = count > MAXDEG ? MAXDEG : count;
}

// ---------------------------------------------------------------------------
// GEMM1 tile (device): Wh1[64 x 128] fp16 = x(f32->f16) @ W1 col-tile.
// B staged DIRECTLY from W1 (f32, transpose-on-stage) -> no W1T prep needed.
// BM=64, BN=128, BK=64; 4 waves (2m x 2n). Epilogue: part-indexed s1/t1
// writes (no atomics, no zeroing): part = (bcol>>7)*2 + (wc>>6).
// ---------------------------------------------------------------------------
__device__ inline void gemm1_tile(const float* __restrict__ x,
                                  const float* __restrict__ W1,
                                  _Float16* __restrict__ Wh1,
                                  const float* __restrict__ a1,
                                  float* __restrict__ s1p, float* __restrict__ t1p,
                                  int brow, int bcol) {
    const int LDT = 72;
    __shared__ _Float16 As[64 * LDT];
    __shared__ _Float16 Bs[128 * LDT];
    const int tid = threadIdx.x;
    const int wid = tid >> 6, lane = tid & 63;
    const int wr = (wid >> 1) * 32, wc = (wid & 1) * 64;
    const int sr = tid >> 3, skg = (tid & 7) * 8;

    f32x4 acc[2][4];
    #pragma unroll
    for (int m = 0; m < 2; ++m)
        #pragma unroll
        for (int n = 0; n < 4; ++n) acc[m][n] = f32x4{0.f, 0.f, 0.f, 0.f};

    for (int k0 = 0; k0 < F_IN; k0 += 64) {
        // stage A (x -> fp16)
        #pragma unroll
        for (int i = 0; i < 2; ++i) {
            int r = sr + i * 32;
            const f32x4* src = (const f32x4*)(x + (size_t)(brow + r) * F_IN + k0 + skg);
            f32x4 a0 = src[0];
            f32x4 a1v = src[1];
            f16x8 av;
            #pragma unroll
            for (int j = 0; j < 4; ++j) { av[j] = (_Float16)a0[j]; av[4 + j] = (_Float16)a1v[j]; }
            *(f16x8*)&As[r * LDT + skg] = av;
        }
        // stage B directly from W1 [512][256] (transpose-on-stage)
        {
            const int cq = (tid & 31) * 4;           // col quad within tile
            const int kbase = tid >> 5;              // 8 k rows per round
            #pragma unroll
            for (int rd = 0; rd < 8; ++rd) {
                int krow = kbase + 8 * rd;
                f32x4 w = *(const f32x4*)&W1[(size_t)(k0 + krow) * F_HID + bcol + cq];
                #pragma unroll
                for (int q = 0; q < 4; ++q)
                    Bs[(cq + q) * LDT + krow] = (_Float16)w[q];
            }
        }
        __syncthreads();
        #pragma unroll
        for (int ks = 0; ks < 2; ++ks) {
            const int kb = ks * 32 + (lane >> 4) * 8;
            f16x8 af[2], bfr[4];
            #pragma unroll
            for (int m = 0; m < 2; ++m)
                af[m] = *(const f16x8*)&As[(wr + m * 16 + (lane & 15)) * LDT + kb];
            #pragma unroll
            for (int n = 0; n < 4; ++n)
                bfr[n] = *(const f16x8*)&Bs[(wc + n * 16 + (lane & 15)) * LDT + kb];
            #pragma unroll
            for (int m = 0; m < 2; ++m)
                #pragma unroll
                for (int n = 0; n < 4; ++n)
                    acc[m][n] = __builtin_amdgcn_mfma_f32_16x16x32_f16(
                        af[m], bfr[n], acc[m][n], 0, 0, 0);
        }
        __syncthreads();
    }
    const int cl = lane & 15;
    const int part = (bcol >> 7) * 2 + (wc >> 6);
    float as[4], at[4];
    #pragma unroll
    for (int n = 0; n < 4; ++n) {
        as[n] = a1[bcol + wc + n * 16 + cl];
        at[n] = a1[F_HID + bcol + wc + n * 16 + cl];
    }
    #pragma unroll
    for (int m = 0; m < 2; ++m) {
        #pragma unroll
        for (int j = 0; j < 4; ++j) {
            float vs = 0.f, vt = 0.f;
            #pragma unroll
            for (int n = 0; n < 4; ++n) { vs += acc[m][n][j] * as[n]; vt += acc[m][n][j] * at[n]; }
            #pragma unroll
            for (int off = 1; off < 16; off <<= 1) {
                vs += __shfl_xor(vs, off);
                vt += __shfl_xor(vt, off);
            }
            if (cl == 0) {
                int row = brow + wr + m * 16 + ((lane >> 4) << 2) + j;
                s1p[part * N_NODES + row] = vs;
                t1p[part * N_NODES + row] = vt;
            }
        }
        #pragma unroll
        for (int n = 0; n < 4; ++n) {
            int row = brow + wr + m * 16 + ((lane >> 4) << 2);
            int col = bcol + wc + n * 16 + cl;
            #pragma unroll
            for (int j = 0; j < 4; ++j)
                Wh1[(size_t)(row + j) * F_HID + col] = (_Float16)acc[m][n][j];
        }
    }
}

// ---------------------------------------------------------------------------
// W2 transpose tile job (32x32): W2 [256][512] f32 -> W2T [512][256] fp16.
// ---------------------------------------------------------------------------
__device__ inline void w2T_tile(int t, const float* __restrict__ W2,
                                _Float16* __restrict__ W2T) {
    __shared__ float Ws[32][33];
    const int kt = t & 7, nt = t >> 3;   // k-tile of 256, n-tile of 512
    const int tx = threadIdx.x & 31, ty = threadIdx.x >> 5;  // 32 x 8
    #pragma unroll
    for (int i = 0; i < 4; ++i)
        Ws[ty + 8 * i][tx] = W2[(size_t)(kt * 32 + ty + 8 * i) * F_IN + nt * 32 + tx];
    __syncthreads();
    #pragma unroll
    for (int i = 0; i < 4; ++i)
        W2T[(size_t)(nt * 32 + ty + 8 * i) * F_HID + kt * 32 + tx] = (_Float16)Ws[tx][ty + 8 * i];
}

// ---------------------------------------------------------------------------
// w2s/w2t job: w2s[k] = W2[k,:] . a2[0:512], w2t[k] = W2[k,:] . a2[512:].
// ---------------------------------------------------------------------------
__device__ inline void w2vec_job(int t, const float* __restrict__ W2,
                                 const float* __restrict__ a2,
                                 float* __restrict__ w2s, float* __restrict__ w2t) {
    const int r = t * 64 + (threadIdx.x >> 2);
    const int q = threadIdx.x & 3;
    float ss = 0.f, tt = 0.f;
    for (int n = q * 4; n < F_IN; n += 16) {
        f32x4 w  = *(const f32x4*)&W2[(size_t)r * F_IN + n];
        f32x4 as = *(const f32x4*)&a2[n];
        f32x4 at = *(const f32x4*)&a2[F_IN + n];
        #pragma unroll
        for (int j = 0; j < 4; ++j) { ss += w[j] * as[j]; tt += w[j] * at[j]; }
    }
    ss += __shfl_xor(ss, 1); ss += __shfl_xor(ss, 2);
    tt += __shfl_xor(tt, 1); tt += __shfl_xor(tt, 2);
    if (q == 0) { w2s[r] = ss; w2t[r] = tt; }
}

// ---------------------------------------------------------------------------
// Kernel A: gemm1 (256 jobs, low bids) + W2T/w2vec prep (132) + csr (2048).
// ---------------------------------------------------------------------------
__global__ __launch_bounds__(256)
void front_kernel(const float* __restrict__ adj, int* __restrict__ cols,
                  int* __restrict__ cnt, const float* __restrict__ x,
                  const float* __restrict__ W1, const float* __restrict__ a1,
                  _Float16* __restrict__ Wh1,
                  float* __restrict__ s1p, float* __restrict__ t1p,
                  const float* __restrict__ W2, const float* __restrict__ a2,
                  _Float16* __restrict__ W2T,
                  float* __restrict__ w2s, float* __restrict__ w2t) {
    const int bid = blockIdx.x;
    if (bid < 256) {
        gemm1_tile(x, W1, Wh1, a1, s1p, t1p, (bid & 127) * 64, (bid >> 7) * 128);
    } else if (bid < 384) {
        w2T_tile(bid - 256, W2, W2T);
    } else if (bid < 388) {
        w2vec_job(bid - 384, W2, a2, w2s, w2t);
    } else {
        const int q = bid - 388;                        // quad in [0, 2048)
        const int row = q * 4 + (threadIdx.x >> 6);
        csr_row(adj, cols, cnt, row, threadIdx.x & 63);
    }
}

// ---------------------------------------------------------------------------
// Kernel B: layer-1 aggregate (R9 structure): softmax(s1,t1 from 4 parts),
// gather Wh1 fp16, ELU, write enc f32 (NT) + enc16; epilogue s2/t2.
// ---------------------------------------------------------------------------
__global__ __launch_bounds__(256)
void aggregate_l1(const _Float16* __restrict__ Wh,
                  const int* __restrict__ cols, const int* __restrict__ cnt,
                  const float* __restrict__ s1p, const float* __restrict__ t1p,
                  const float* __restrict__ w2s, const float* __restrict__ w2t,
                  float* __restrict__ enc, _Float16* __restrict__ enc16,
                  float* __restrict__ s2, float* __restrict__ t2) {
    const int wid = threadIdx.x >> 6, lane = threadIdx.x & 63;
    const int row = blockIdx.x * 4 + wid;
    const int deg = cnt[row];
    __shared__ float pS[4][64];
    __shared__ int jS[4][64];
    const float sI = s1p[row] + s1p[N_NODES + row]
                   + s1p[2 * N_NODES + row] + s1p[3 * N_NODES + row];
    int j = 0;
    float ev = -1e30f;
    if (lane < deg) {
        j = cols[(size_t)row * MAXDEG + lane];
        float tj = t1p[j] + t1p[N_NODES + j]
                 + t1p[2 * N_NODES + j] + t1p[3 * N_NODES + j];
        float z = sI + tj;
        ev = z > 0.0f ? z : ALPHA * z;
    }
    float m = ev;
    #pragma unroll
    for (int off = 32; off > 0; off >>= 1) m = fmaxf(m, __shfl_xor(m, off));
    float ex = (lane < deg) ? __expf(ev - m) : 0.0f;
    float sum = ex;
    #pragma unroll
    for (int off = 32; off > 0; off >>= 1) sum += __shfl_xor(sum, off);
    pS[wid][lane] = ex / sum;
    jS[wid][lane] = j;
    __syncthreads();

    float acc[4] = {};
    const size_t lo = (size_t)lane * 4;
    int d = 0;
    for (; d + 4 <= deg; d += 4) {
        float p0 = pS[wid][d],     p1 = pS[wid][d + 1];
        float p2 = pS[wid][d + 2], p3 = pS[wid][d + 3];
        f16x4 v0 = *(const f16x4*)(Wh + (size_t)jS[wid][d] * F_HID + lo);
        f16x4 v1 = *(const f16x4*)(Wh + (size_t)jS[wid][d + 1] * F_HID + lo);
        f16x4 v2 = *(const f16x4*)(Wh + (size_t)jS[wid][d + 2] * F_HID + lo);
        f16x4 v3 = *(const f16x4*)(Wh + (size_t)jS[wid][d + 3] * F_HID + lo);
        #pragma unroll
        for (int jj = 0; jj < 4; ++jj)
            acc[jj] += p0 * (float)v0[jj] + p1 * (float)v1[jj]
                     + p2 * (float)v2[jj] + p3 * (float)v3[jj];
    }
    for (; d < deg; ++d) {
        float p = pS[wid][d];
        f16x4 w = *(const f16x4*)(Wh + (size_t)jS[wid][d] * F_HID + lo);
        #pragma unroll
        for (int jj = 0; jj < 4; ++jj) acc[jj] += p * (float)w[jj];
    }
    f32x4 o; f16x4 h;
    #pragma unroll
    for (int jj = 0; jj < 4; ++jj) {
        float v = acc[jj];
        float e = v > 0.0f ? v : (__expf(v) - 1.0f);
        o[jj] = e; h[jj] = (_Float16)e;
    }
    __builtin_nontemporal_store(o, (f32x4*)(enc + (size_t)row * F_HID + lo));
    *(f16x4*)(enc16 + (size_t)row * F_HID + lo) = h;

    f32x4 ws = *(const f32x4*)(w2s + lo);
    f32x4 wt = *(const f32x4*)(w2t + lo);
    float ps = 0.f, pt = 0.f;
    #pragma unroll
    for (int jj = 0; jj < 4; ++jj) { ps += o[jj] * ws[jj]; pt += o[jj] * wt[jj]; }
    #pragma unroll
    for (int off = 32; off > 0; off >>= 1) {
        ps += __shfl_xor(ps, off);
        pt += __shfl_xor(pt, off);
    }
    if (lane == 0) { s2[row] = ps; t2[row] = pt; }
}

// ---------------------------------------------------------------------------
// Kernel C: layer-2 pre-aggregate (linearity): aggE = att2 @ enc (fp16).
// ---------------------------------------------------------------------------
__global__ __launch_bounds__(256)
void aggregate_l2pre(const _Float16* __restrict__ enc16,
                     const int* __restrict__ cols, const int* __restrict__ cnt,
                     const float* __restrict__ s, const float* __restrict__ t,
                     _Float16* __restrict__ aggE16) {
    const int wid = threadIdx.x >> 6, lane = threadIdx.x & 63;
    const int row = blockIdx.x * 4 + wid;
    const int deg = cnt[row];
    __shared__ float pS[4][64];
    __shared__ int jS[4][64];
    int j = 0;
    float ev = -1e30f;
    if (lane < deg) {
        j = cols[(size_t)row * MAXDEG + lane];
        float z = s[row] + t[j];
        ev = z > 0.0f ? z : ALPHA * z;
    }
    float m = ev;
    #pragma unroll
    for (int off = 32; off > 0; off >>= 1) m = fmaxf(m, __shfl_xor(m, off));
    float ex = (lane < deg) ? __expf(ev - m) : 0.0f;
    float sum = ex;
    #pragma unroll
    for (int off = 32; off > 0; off >>= 1) sum += __shfl_xor(sum, off);
    pS[wid][lane] = ex / sum;
    jS[wid][lane] = j;
    __syncthreads();

    float acc[4] = {};
    const size_t lo = (size_t)lane * 4;
    int d = 0;
    for (; d + 4 <= deg; d += 4) {
        float p0 = pS[wid][d],     p1 = pS[wid][d + 1];
        float p2 = pS[wid][d + 2], p3 = pS[wid][d + 3];
        f16x4 v0 = *(const f16x4*)(enc16 + (size_t)jS[wid][d] * F_HID + lo);
        f16x4 v1 = *(const f16x4*)(enc16 + (size_t)jS[wid][d + 1] * F_HID + lo);
        f16x4 v2 = *(const f16x4*)(enc16 + (size_t)jS[wid][d + 2] * F_HID + lo);
        f16x4 v3 = *(const f16x4*)(enc16 + (size_t)jS[wid][d + 3] * F_HID + lo);
        #pragma unroll
        for (int jj = 0; jj < 4; ++jj)
            acc[jj] += p0 * (float)v0[jj] + p1 * (float)v1[jj]
                     + p2 * (float)v2[jj] + p3 * (float)v3[jj];
    }
    for (; d < deg; ++d) {
        float p = pS[wid][d];
        f16x4 w = *(const f16x4*)(enc16 + (size_t)jS[wid][d] * F_HID + lo);
        #pragma unroll
        for (int jj = 0; jj < 4; ++jj) acc[jj] += p * (float)w[jj];
    }
    f16x4 h;
    #pragma unroll
    for (int jj = 0; jj < 4; ++jj) h[jj] = (_Float16)acc[jj];
    *(f16x4*)(aggE16 + (size_t)row * F_HID + lo) = h;
}

// ---------------------------------------------------------------------------
// Kernel D: dec[8192,512] f32 = elu( aggE16[8192,256] @ W2 ). BM=128, BN=64,
// B panel resident in LDS; ELU fused; NT f32 stores.
// ---------------------------------------------------------------------------
__global__ __launch_bounds__(256)
void gemm2e(const _Float16* __restrict__ A, const _Float16* __restrict__ BT,
            float* __restrict__ C) {
    const int LDT = 72, LDB = 264;
    __shared__ _Float16 As[128 * LDT];
    __shared__ _Float16 Bs[64 * LDB];
    const int tid = threadIdx.x;
    const int wid = tid >> 6, lane = tid & 63;
    const int brow = (blockIdx.x >> 3) * 128;
    const int bcol = (blockIdx.x & 7) * 64;
    const int wr = (wid >> 1) * 64, wc = (wid & 1) * 32;

    #pragma unroll
    for (int i = 0; i < 8; ++i) {
        int id = tid + i * 256;
        int r = id >> 5, kc = (id & 31) * 8;
        *(f16x8*)&Bs[r * LDB + kc] = *(const f16x8*)&BT[(size_t)(bcol + r) * F_HID + kc];
    }

    f32x4 acc[4][2];
    #pragma unroll
    for (int m = 0; m < 4; ++m)
        #pragma unroll
        for (int n = 0; n < 2; ++n) acc[m][n] = f32x4{0.f, 0.f, 0.f, 0.f};

    for (int k0 = 0; k0 < F_HID; k0 += 64) {
        #pragma unroll
        for (int i = 0; i < 4; ++i) {
            int id = tid + i * 256;
            int r = id >> 3, kc = (id & 7) * 8;
            *(f16x8*)&As[r * LDT + kc] = *(const f16x8*)&A[(size_t)(brow + r) * F_HID + k0 + kc];
        }
        __syncthreads();
        #pragma unroll
        for (int ks = 0; ks < 2; ++ks) {
            const int kb = ks * 32 + (lane >> 4) * 8;
            f16x8 af[4], bfr[2];
            #pragma unroll
            for (int m = 0; m < 4; ++m)
                af[m] = *(const f16x8*)&As[(wr + m * 16 + (lane & 15)) * LDT + kb];
            #pragma unroll
            for (int n = 0; n < 2; ++n)
                bfr[n] = *(const f16x8*)&Bs[(wc + n * 16 + (lane & 15)) * LDB + k0 + kb];
            #pragma unroll
            for (int m = 0; m < 4; ++m)
                #pragma unroll
                for (int n = 0; n < 2; ++n)
                    acc[m][n] = __builtin_amdgcn_mfma_f32_16x16x32_f16(
                        af[m], bfr[n], acc[m][n], 0, 0, 0);
        }
        __syncthreads();
    }
    #pragma unroll
    for (int m = 0; m < 4; ++m)
        #pragma unroll
        for (int n = 0; n < 2; ++n) {
            int row = brow + wr + m * 16 + ((lane >> 4) << 2);
            int col = bcol + wc + n * 16 + (lane & 15);
            #pragma unroll
            for (int j = 0; j < 4; ++j) {
                float v = acc[m][n][j];
                float e = v > 0.0f ? v : (__expf(v) - 1.0f);
                __builtin_nontemporal_store(e, &C[(size_t)(row + j) * F_IN + col]);
            }
        }
}

// ---------------------------------------------------------------------------
extern "C" void kernel_launch(void* const* d_in, const int* in_sizes, int n_in,
                              void* d_out, int out_size, void* d_ws, size_t ws_size,
                              hipStream_t stream) {
    (void)in_sizes; (void)n_in; (void)out_size; (void)ws_size;
    const float* x   = (const float*)d_in[0];
    const float* adj = (const float*)d_in[1];
    const float* W1  = (const float*)d_in[2];
    const float* a1  = (const float*)d_in[3];
    const float* W2  = (const float*)d_in[4];
    const float* a2  = (const float*)d_in[5];

    float* dec = (float*)d_out;                           // [8192, 512] f32
    float* enc = dec + (size_t)N_NODES * F_IN;            // [8192, 256] f32

    int*      cols   = (int*)d_ws;                        // 8192*64
    int*      cnt    = cols + (size_t)N_NODES * MAXDEG;   // 8192
    float*    s1p    = (float*)(cnt + N_NODES);           // 4*8192 (parts)
    float*    t1p    = s1p + 4 * N_NODES;                 // 4*8192 (parts)
    float*    s2     = t1p + 4 * N_NODES;                 // 8192
    float*    t2     = s2 + N_NODES;                      // 8192
    float*    w2s    = t2 + N_NODES;                      // 256
    float*    w2t    = w2s + F_HID;                       // 256
    _Float16* Wh1    = (_Float16*)(w2t + F_HID);          // 8192*256 fp16
    _Float16* enc16  = Wh1 + (size_t)N_NODES * F_HID;     // 8192*256 fp16
    _Float16* aggE16 = enc16 + (size_t)N_NODES * F_HID;   // 8192*256 fp16
    _Float16* W2T    = aggE16 + (size_t)N_NODES * F_HID;  // 512*256 fp16

    // A. csr (all rows) || gemm1 (direct-W1 staging) || W2T/w2vec prep
    front_kernel<<<2436, 256, 0, stream>>>(adj, cols, cnt, x, W1, a1, Wh1,
                                           s1p, t1p, W2, a2, W2T, w2s, w2t);

    // B. layer-1 attention -> enc, enc16; epilogue s2/t2
    aggregate_l1<<<N_NODES / 4, 256, 0, stream>>>(Wh1, cols, cnt, s1p, t1p,
                                                  w2s, w2t, enc, enc16, s2, t2);

    // C. layer-2 aggregate in input space: aggE = att2 @ enc
    aggregate_l2pre<<<N_NODES / 4, 256, 0, stream>>>(enc16, cols, cnt, s2, t2, aggE16);

    // D. dec = elu(aggE @ W2)
    gemm2e<<<512, 256, 0, stream>>>(aggE16, W2T, dec);
}